// Round 7
// baseline (576.823 us; speedup 1.0000x reference)
//
#include <hip/hip_runtime.h>
#include <hip/hip_bf16.h>
#include <math.h>

#define BATCH 64
#define TLEN 512
#define DIM 768
#define NLAB 50

typedef __attribute__((ext_vector_type(8))) short short8;   // 8 bf16 (4 VGPRs)
typedef __attribute__((ext_vector_type(4))) float f32x4;    // MFMA acc

__device__ __forceinline__ unsigned short f2bf(float f) {
    unsigned int u = __float_as_uint(f);
    return (unsigned short)((u + 0x7FFFu + ((u >> 16) & 1u)) >> 16);
}

// single-wave LDS fence: legal ONLY for 64-thread (one-wave) blocks.
__device__ __forceinline__ void wave_lds_fence() {
    __asm__ __volatile__("s_waitcnt lgkmcnt(0)" ::: "memory");
    __builtin_amdgcn_wave_barrier();
}

// ---------------------------------------------------------------------------
// prep: W fp32 [768 x 50] -> Bt bf16 [64 cols][768 k]; zero out[0] for atomics
// ---------------------------------------------------------------------------
__global__ __launch_bounds__(256) void wprep_kernel(const float* __restrict__ W,
                                                    unsigned short* __restrict__ Bt,
                                                    float* __restrict__ out0) {
    int idx = blockIdx.x * 256 + threadIdx.x;
    if (idx == 0) out0[0] = 0.f;
    if (idx < 64 * DIM) {
        int c = idx / DIM;
        int k = idx - c * DIM;
        float v = (c < NLAB) ? W[k * NLAB + c] : 0.f;
        Bt[idx] = f2bf(v);
    }
}

// ---------------------------------------------------------------------------
// GEMM: 512 thr / 8 waves, tile 128x64, dbuf LDS. Epilogue also writes
// exp(logits) to an ALIGNED workspace buffer (eexp) for the CRF scan.
// ---------------------------------------------------------------------------
#define AST 36
#define BSTC 40

__global__ __launch_bounds__(512)
void gemm_kernel(
    const float* __restrict__ A,
    const unsigned short* __restrict__ Bt,
    const float* __restrict__ bias,
    float* __restrict__ out,
    float* __restrict__ eexp)                 // may be null
{
    __shared__ float As[2][128 * AST];
    __shared__ short Bs[2][64 * BSTC];

    const int tid = threadIdx.x;
    const int wave = tid >> 6;
    const int lane = tid & 63;
    const int m = lane & 15;
    const int q = lane >> 4;
    const int row0 = blockIdx.x * 128;

    const int r0s = tid >> 2;
    const int c0s = (tid & 3) * 8;
    const int bcol = tid >> 3;
    const int bkk = (tid & 7) * 4;

    f32x4 acc0 = {0.f,0.f,0.f,0.f}, acc1 = {0.f,0.f,0.f,0.f};
    f32x4 acc2 = {0.f,0.f,0.f,0.f}, acc3 = {0.f,0.f,0.f,0.f};

    {
        *(float4*)&As[0][r0s * AST + c0s]     = *(const float4*)(A + (size_t)(row0 + r0s) * DIM + c0s);
        *(float4*)&As[0][r0s * AST + c0s + 4] = *(const float4*)(A + (size_t)(row0 + r0s) * DIM + c0s + 4);
        *(short4*)&Bs[0][bcol * BSTC + bkk]   = *(const short4*)(Bt + (size_t)bcol * DIM + bkk);
    }
    __syncthreads();

    int buf = 0;
    for (int ch = 0; ch < DIM / 32; ++ch) {
        const int k0n = (ch + 1) * 32;
        const bool havenext = (ch < DIM / 32 - 1);
        float4 pa0, pa1;
        short4 pb;
        if (havenext) {
            pa0 = *(const float4*)(A + (size_t)(row0 + r0s) * DIM + k0n + c0s);
            pa1 = *(const float4*)(A + (size_t)(row0 + r0s) * DIM + k0n + c0s + 4);
            pb  = *(const short4*)(Bt + (size_t)bcol * DIM + k0n + bkk);
        }

        const short8 bq0 = *(const short8*)&Bs[buf][( 0 + m) * BSTC + q * 8];
        const short8 bq1 = *(const short8*)&Bs[buf][(16 + m) * BSTC + q * 8];
        const short8 bq2 = *(const short8*)&Bs[buf][(32 + m) * BSTC + q * 8];
        const short8 bq3 = *(const short8*)&Bs[buf][(48 + m) * BSTC + q * 8];

        {
            const int rr = wave * 16 + m;
            const float4 xa = *(const float4*)&As[buf][rr * AST + q * 8];
            const float4 xb = *(const float4*)&As[buf][rr * AST + q * 8 + 4];
            short8 af;
            af[0] = (short)f2bf(xa.x); af[1] = (short)f2bf(xa.y);
            af[2] = (short)f2bf(xa.z); af[3] = (short)f2bf(xa.w);
            af[4] = (short)f2bf(xb.x); af[5] = (short)f2bf(xb.y);
            af[6] = (short)f2bf(xb.z); af[7] = (short)f2bf(xb.w);
            acc0 = __builtin_amdgcn_mfma_f32_16x16x32_bf16(af, bq0, acc0, 0, 0, 0);
            acc1 = __builtin_amdgcn_mfma_f32_16x16x32_bf16(af, bq1, acc1, 0, 0, 0);
            acc2 = __builtin_amdgcn_mfma_f32_16x16x32_bf16(af, bq2, acc2, 0, 0, 0);
            acc3 = __builtin_amdgcn_mfma_f32_16x16x32_bf16(af, bq3, acc3, 0, 0, 0);
        }

        if (havenext) {
            const int nb = buf ^ 1;
            *(float4*)&As[nb][r0s * AST + c0s]     = pa0;
            *(float4*)&As[nb][r0s * AST + c0s + 4] = pa1;
            *(short4*)&Bs[nb][bcol * BSTC + bkk]   = pb;
        }
        __syncthreads();
        buf ^= 1;
    }

    const int rb = row0 + wave * 16 + q * 4;
#pragma unroll
    for (int nt = 0; nt < 4; ++nt) {
        const f32x4 av = (nt == 0) ? acc0 : (nt == 1) ? acc1 : (nt == 2) ? acc2 : acc3;
        const int col = nt * 16 + m;
        if (col < NLAB) {
            const float bv = bias[col];
#pragma unroll
            for (int r = 0; r < 4; ++r) {
                const float v = av[r] + bv;
                out[(size_t)(rb + r) * NLAB + col] = v;
                if (eexp) eexp[(size_t)(rb + r) * NLAB + col] = __expf(v);
            }
        }
    }
}

// ---------------------------------------------------------------------------
// CRF v13: v12 + PINNED emission prefetch.
// R6 forensics: VGPR=132 (pipeline needs ~190), WRITE_SIZE~0 (no spill) =>
// compiler SANK the prefetch loads to their use (its legal response to
// pressure), collapsing the 3-stage pipeline to depth 0 -> ~900cy cross-XCD
// load latency exposed every step (1440 cyc/step observed vs ~400 work).
// Fix: asm volatile("" : "+v"(x)) keep-alive pins right after each staged
// load (volatile asm can't move; load can't sink past its consumer) and
// prefetch distance 2 -> 3 (s0..s2 live, s3 loaded in-loop).
// ---------------------------------------------------------------------------
#define LOG2E 1.44269504088896340736f
#define LN2   0.69314718055994530942f

#define PIN(sx) { _Pragma("unroll")                                             \
    for (int mt_ = 0; mt_ < 4; ++mt_)                                           \
        asm volatile("" : "+v"(sx[mt_][0]), "+v"(sx[mt_][1]),                   \
                          "+v"(sx[mt_][2]), "+v"(sx[mt_][3])); }

template<bool EEX>
__global__ __launch_bounds__(64) __attribute__((amdgpu_waves_per_eu(1, 1)))
void crf_kernel(
    const float* __restrict__ logits,
    const float* __restrict__ eex,
    const int* __restrict__ labels,
    const void* __restrict__ maskp,
    const float* __restrict__ startT,
    const float* __restrict__ endT,
    const float* __restrict__ trans,
    float* __restrict__ out0) {
    const int lane = threadIdx.x;
    const int b16 = lane & 15;           // batch within block
    const int g = lane >> 4;             // quad group
    const int b = blockIdx.x * 16 + b16; // global batch

    __shared__ __align__(16) unsigned short X[16 * 64]; // [batch][label] bf16
    char* xc = (char*)X;

    // ---- len_b: chunked mask scan (chunk c = g covers 128 t's) ----
    const int probe = ((const int*)maskp)[0];
    int len = 0;
    {
        const int t0 = g * 128;
        if (probe == 1) {
            const int* mk = (const int*)maskp + (size_t)b * TLEN + t0;
#pragma unroll 8
            for (int i = 0; i < 128; ++i) len += (mk[i] != 0);
        } else if (probe == 0x01010101) {
            const unsigned char* mk = (const unsigned char*)maskp + (size_t)b * TLEN + t0;
#pragma unroll 8
            for (int i = 0; i < 128; ++i) len += (mk[i] != 0);
        } else if (probe == 0x3F803F80) {
            const unsigned short* mk = (const unsigned short*)maskp + (size_t)b * TLEN + t0;
#pragma unroll 8
            for (int i = 0; i < 128; ++i) len += (mk[i] != 0);
        } else {
            const float* mk = (const float*)maskp + (size_t)b * TLEN + t0;
#pragma unroll 8
            for (int i = 0; i < 128; ++i) len += (mk[i] != 0.f);
        }
    }
    len += __shfl_xor(len, 16, 64);
    len += __shfl_xor(len, 32, 64);
    int lenmax = len;
    { int o = __shfl_xor(lenmax, 1, 64); lenmax = lenmax > o ? lenmax : o; }
    { int o = __shfl_xor(lenmax, 2, 64); lenmax = lenmax > o ? lenmax : o; }
    { int o = __shfl_xor(lenmax, 4, 64); lenmax = lenmax > o ? lenmax : o; }
    { int o = __shfl_xor(lenmax, 8, 64); lenmax = lenmax > o ? lenmax : o; }

    // ---- E^T fragments: A[m][k] = exp(trans[k][m]), hi/lo bf16, zero-pad ----
    short8 ah00, ah01, ah02, ah03, ah10, ah11, ah12, ah13;
    short8 al00, al01, al02, al03, al10, al11, al12, al13;
#define MKFRAG(DH, DL, KT, MT) { short8 h, l;                                   \
    _Pragma("unroll")                                                           \
    for (int j = 0; j < 8; ++j) {                                               \
        const int k = 32 * KT + 8 * g + j; const int m = 16 * MT + b16;         \
        float e = 0.f;                                                          \
        if (k < NLAB && m < NLAB) e = __expf(trans[k * NLAB + m]);              \
        const unsigned short hb = f2bf(e);                                      \
        const float ef = __uint_as_float((unsigned)hb << 16);                   \
        const unsigned short lb = f2bf(e - ef);                                 \
        h[j] = (short)hb; l[j] = (short)lb;                                     \
    } DH = h; DL = l; }
    MKFRAG(ah00, al00, 0, 0) MKFRAG(ah01, al01, 0, 1)
    MKFRAG(ah02, al02, 0, 2) MKFRAG(ah03, al03, 0, 3)
    MKFRAG(ah10, al10, 1, 0) MKFRAG(ah11, al11, 1, 1)
    MKFRAG(ah12, al12, 1, 2) MKFRAG(ah13, al13, 1, 3)

    // ---- addresses / per-lane label maps ----
    const int rowbase = b16 * 128;
    const int swz = (b16 & 7) << 4;
    int wby[4];                          // 8B write addr per mt
    int emo[4][4];
    bool vmask[4][4];
#pragma unroll
    for (int mt = 0; mt < 4; ++mt) {
        wby[mt] = rowbase + ((32 * mt + 8 * g) ^ swz);
#pragma unroll
        for (int r = 0; r < 4; ++r) {
            const int L = 16 * mt + 4 * g + r;
            emo[mt][r] = (L < NLAB) ? L : (NLAB - 1);
            vmask[mt][r] = (L < NLAB);
        }
    }
    const int rby0 = rowbase + ((16 * g)      ^ swz);
    const int rby1 = rowbase + ((64 + 16 * g) ^ swz);

    const float* emb = logits + (size_t)b * TLEN * NLAB;
    const float* emsrc = EEX ? (eex + (size_t)b * TLEN * NLAB) : emb;

    // ---- prologue: alpha0 = startT + em[0]; X0 = exp(a0 - a0[label0]) ----
    float a0[4][4];
#pragma unroll
    for (int mt = 0; mt < 4; ++mt)
#pragma unroll
        for (int r = 0; r < 4; ++r)
            a0[mt][r] = startT[emo[mt][r]] + emb[emo[mt][r]];
    const float a00 = __int_as_float(
        __builtin_amdgcn_ds_bpermute(b16 * 4, __float_as_int(a0[0][0])));
    float A = a00;

#pragma unroll
    for (int mt = 0; mt < 4; ++mt) {
        float w0 = vmask[mt][0] ? __expf(a0[mt][0] - a00) : 0.f;
        float w1 = vmask[mt][1] ? __expf(a0[mt][1] - a00) : 0.f;
        float w2 = vmask[mt][2] ? __expf(a0[mt][2] - a00) : 0.f;
        float w3 = vmask[mt][3] ? __expf(a0[mt][3] - a00) : 0.f;
        unsigned int u0, u1;
        asm("v_cvt_pk_bf16_f32 %0, %1, %2" : "=v"(u0) : "v"(w0), "v"(w1));
        asm("v_cvt_pk_bf16_f32 %0, %1, %2" : "=v"(u1) : "v"(w2), "v"(w3));
        uint2 p; p.x = u0; p.y = u1;
        *(uint2*)(xc + wby[mt]) = p;
    }
    wave_lds_fence();
    short8 xb0 = *(const short8*)(xc + rby0);
    short8 xb1 = *(const short8*)(xc + rby1);

    // emission stage loads: EEX -> float2 pairs (aligned ws), else scalars
#define LOADSTAGE(dst, row) {                                                   \
        const float* ep = emsrc + (size_t)(row) * NLAB;                         \
        _Pragma("unroll")                                                       \
        for (int mt_ = 0; mt_ < 4; ++mt_) {                                     \
            if constexpr (EEX) {                                                \
                const float2 p0_ = *(const float2*)(ep + 16 * mt_ + 4 * g);     \
                const float2 p1_ = *(const float2*)(ep + 16 * mt_ + 4 * g + 2); \
                dst[mt_][0] = p0_.x; dst[mt_][1] = p0_.y;                       \
                dst[mt_][2] = p1_.x; dst[mt_][3] = p1_.y;                       \
            } else {                                                            \
                _Pragma("unroll")                                               \
                for (int r_ = 0; r_ < 4; ++r_)                                  \
                    dst[mt_][r_] = ep[emo[mt_][r_]];                            \
            }                                                                   \
        } }

    float s0[4][4], s1[4][4], s2[4][4];
    LOADSTAGE(s0, 1)                                        PIN(s0)
    LOADSTAGE(s1, (2 < lenmax) ? 2 : (lenmax - 1))          PIN(s1)
    LOADSTAGE(s2, (3 < lenmax) ? 3 : (lenmax - 1))          PIN(s2)
    float vwf = 1.0f;   // raw scale X(t-1)[label0]; exp(a00-a00)=1 at t=1

    const f32x4 z4 = {0.f, 0.f, 0.f, 0.f};

#pragma unroll 2
    for (int t = 1; t < lenmax; ++t) {
        const bool act = (t < len);
        const float lg2v = __log2f(vwf);
        const float rv = __builtin_amdgcn_rcpf(vwf);
        A += act ? lg2v * LN2 : 0.f;

        // prefetch emissions for t+3 (issued HERE; pin prevents sinking)
        float s3[4][4];
        { int tn = t + 3; tn = (tn < lenmax) ? tn : (lenmax - 1); LOADSTAGE(s3, tn) }
        PIN(s3)

        // pe = exp(em)/v, masked (also kills garbage from padded labels)
        float pe[4][4];
#pragma unroll
        for (int mt = 0; mt < 4; ++mt)
#pragma unroll
            for (int r = 0; r < 4; ++r) {
                float p;
                if constexpr (EEX) p = s0[mt][r] * rv;
                else p = __builtin_amdgcn_exp2f(fmaf(s0[mt][r], LOG2E, -lg2v));
                pe[mt][r] = vmask[mt][r] ? p : 0.f;
            }

        // r = E^T X : hi/lo split accumulators, chains of depth 2
        f32x4 h0 = __builtin_amdgcn_mfma_f32_16x16x32_bf16(ah00, xb0, z4, 0, 0, 0);
        h0 = __builtin_amdgcn_mfma_f32_16x16x32_bf16(ah10, xb1, h0, 0, 0, 0);
        f32x4 l0 = __builtin_amdgcn_mfma_f32_16x16x32_bf16(al00, xb0, z4, 0, 0, 0);
        l0 = __builtin_amdgcn_mfma_f32_16x16x32_bf16(al10, xb1, l0, 0, 0, 0);
        f32x4 h1 = __builtin_amdgcn_mfma_f32_16x16x32_bf16(ah01, xb0, z4, 0, 0, 0);
        h1 = __builtin_amdgcn_mfma_f32_16x16x32_bf16(ah11, xb1, h1, 0, 0, 0);
        f32x4 l1 = __builtin_amdgcn_mfma_f32_16x16x32_bf16(al01, xb0, z4, 0, 0, 0);
        l1 = __builtin_amdgcn_mfma_f32_16x16x32_bf16(al11, xb1, l1, 0, 0, 0);
        f32x4 h2 = __builtin_amdgcn_mfma_f32_16x16x32_bf16(ah02, xb0, z4, 0, 0, 0);
        h2 = __builtin_amdgcn_mfma_f32_16x16x32_bf16(ah12, xb1, h2, 0, 0, 0);
        f32x4 l2 = __builtin_amdgcn_mfma_f32_16x16x32_bf16(al02, xb0, z4, 0, 0, 0);
        l2 = __builtin_amdgcn_mfma_f32_16x16x32_bf16(al12, xb1, l2, 0, 0, 0);
        f32x4 h3 = __builtin_amdgcn_mfma_f32_16x16x32_bf16(ah03, xb0, z4, 0, 0, 0);
        h3 = __builtin_amdgcn_mfma_f32_16x16x32_bf16(ah13, xb1, h3, 0, 0, 0);
        f32x4 l3 = __builtin_amdgcn_mfma_f32_16x16x32_bf16(al03, xb0, z4, 0, 0, 0);
        l3 = __builtin_amdgcn_mfma_f32_16x16x32_bf16(al13, xb1, l3, 0, 0, 0);

        const float w00 = (h0[0] + l0[0]) * pe[0][0];
        const float w01 = (h0[1] + l0[1]) * pe[0][1];
        const float w02 = (h0[2] + l0[2]) * pe[0][2];
        const float w03 = (h0[3] + l0[3]) * pe[0][3];
        const float w10 = (h1[0] + l1[0]) * pe[1][0];
        const float w11 = (h1[1] + l1[1]) * pe[1][1];
        const float w12 = (h1[2] + l1[2]) * pe[1][2];
        const float w13 = (h1[3] + l1[3]) * pe[1][3];
        const float w20 = (h2[0] + l2[0]) * pe[2][0];
        const float w21 = (h2[1] + l2[1]) * pe[2][1];
        const float w22 = (h2[2] + l2[2]) * pe[2][2];
        const float w23 = (h2[3] + l2[3]) * pe[2][3];
        const float w30 = (h3[0] + l3[0]) * pe[3][0];
        const float w31 = (h3[1] + l3[1]) * pe[3][1];
        const float w32 = (h3[2] + l3[2]) * pe[3][2];
        const float w33 = (h3[3] + l3[3]) * pe[3][3];

        // next-step scale: raw fp32 label0 value, broadcast down the column
        const float vwn = __int_as_float(
            __builtin_amdgcn_ds_bpermute(b16 * 4, __float_as_int(w00)));

        uint2 p0, p1, p2, p3;
        asm("v_cvt_pk_bf16_f32 %0, %1, %2" : "=v"(p0.x) : "v"(w00), "v"(w01));
        asm("v_cvt_pk_bf16_f32 %0, %1, %2" : "=v"(p0.y) : "v"(w02), "v"(w03));
        asm("v_cvt_pk_bf16_f32 %0, %1, %2" : "=v"(p1.x) : "v"(w10), "v"(w11));
        asm("v_cvt_pk_bf16_f32 %0, %1, %2" : "=v"(p1.y) : "v"(w12), "v"(w13));
        asm("v_cvt_pk_bf16_f32 %0, %1, %2" : "=v"(p2.x) : "v"(w20), "v"(w21));
        asm("v_cvt_pk_bf16_f32 %0, %1, %2" : "=v"(p2.y) : "v"(w22), "v"(w23));
        asm("v_cvt_pk_bf16_f32 %0, %1, %2" : "=v"(p3.x) : "v"(w30), "v"(w31));
        asm("v_cvt_pk_bf16_f32 %0, %1, %2" : "=v"(p3.y) : "v"(w32), "v"(w33));

        if (act) {   // frozen batches keep their previous X
            *(uint2*)(xc + wby[0]) = p0;
            *(uint2*)(xc + wby[1]) = p1;
            *(uint2*)(xc + wby[2]) = p2;
            *(uint2*)(xc + wby[3]) = p3;
        }
        wave_lds_fence();
        xb0 = *(const short8*)(xc + rby0);
        xb1 = *(const short8*)(xc + rby1);

        // rotate emission stages (renamed by unroll / copy coalescing)
#pragma unroll
        for (int mt = 0; mt < 4; ++mt)
#pragma unroll
            for (int r = 0; r < 4; ++r) {
                s0[mt][r] = s1[mt][r];
                s1[mt][r] = s2[mt][r];
                s2[mt][r] = s3[mt][r];
            }
        vwf = vwn;
    }

    // ---- den = A + log( sum_j X[j][b] * exp(endT[j]) ) ----
    float part = 0.f;
#pragma unroll
    for (int j = 0; j < 8; ++j) {
        const int k1 = 32 + 8 * g + j;
        const float x0 = __uint_as_float((unsigned)(unsigned short)xb0[j] << 16);
        const float x1 = __uint_as_float((unsigned)(unsigned short)xb1[j] << 16);
        const float e0 = __expf(endT[8 * g + j]);
        float e1 = 0.f;
        if (k1 < NLAB) e1 = __expf(endT[k1]);
        part = fmaf(x0, e0, part);
        part = fmaf(x1, e1, part);
    }
    part += __shfl_xor(part, 16, 64);
    part += __shfl_xor(part, 32, 64);
    const float den = A + __logf(part);

    // ---- numerator: gold path, chunked over g ----
    const int* tg = labels + (size_t)b * TLEN;
    float num = 0.f;
    {
        const int t0 = g * 128;
#pragma unroll 8
        for (int i = 0; i < 128; ++i) {
            const int t = t0 + i;
            if (t < len) {
                const int tag = tg[t];
                num += emb[(size_t)t * NLAB + tag];
                if (t >= 1) num += trans[tg[t - 1] * NLAB + tag];
            }
        }
    }
    num += __shfl_xor(num, 16, 64);
    num += __shfl_xor(num, 32, 64);
    if (g == 0) {
        num += startT[tg[0]] + endT[tg[len - 1]];
        atomicAdd(out0, (den - num) * (1.0f / BATCH));
    }
}

extern "C" void kernel_launch(void* const* d_in, const int* in_sizes, int n_in,
                              void* d_out, int out_size, void* d_ws, size_t ws_size,
                              hipStream_t stream) {
    (void)in_sizes; (void)n_in; (void)out_size;
    const float* emb    = (const float*)d_in[0];
    const int*   labels = (const int*)d_in[1];
    const void*  mask   = d_in[2];
    const float* W      = (const float*)d_in[3];
    const float* bias   = (const float*)d_in[4];
    const float* startT = (const float*)d_in[5];
    const float* endT   = (const float*)d_in[6];
    const float* trans  = (const float*)d_in[7];

    float* out    = (float*)d_out;
    float* logits = out + 1;
    unsigned short* Bt = (unsigned short*)((char*)d_ws + 512);   // 96 KiB bf16 W^T
    float* eex = (float*)((char*)d_ws + (128 << 10));            // aligned exp(logits)

    const size_t need = (size_t)(128 << 10)
                      + sizeof(float) * ((size_t)BATCH * TLEN * NLAB + 256);
    const bool use_eex = (ws_size >= need);

    wprep_kernel<<<(64 * DIM + 255) / 256, 256, 0, stream>>>(W, Bt, out);
    gemm_kernel<<<(BATCH * TLEN) / 128, 512, 0, stream>>>(emb, Bt, bias, logits,
                                                          use_eex ? eex : nullptr);
    if (use_eex)
        crf_kernel<true><<<BATCH / 16, 64, 0, stream>>>(logits, eex, labels, mask,
                                                        startT, endT, trans, out);
    else
        crf_kernel<false><<<BATCH / 16, 64, 0, stream>>>(logits, nullptr, labels, mask,
                                                         startT, endT, trans, out);
}

// Round 8
// 466.463 us; speedup vs baseline: 1.2366x; 1.2366x over previous
//
#include <hip/hip_runtime.h>
#include <hip/hip_bf16.h>
#include <math.h>

#define BATCH 64
#define TLEN 512
#define DIM 768
#define NLAB 50
#define EEXS 64   // padded eex row stride (floats): 256B, 16B-aligned everywhere

typedef __attribute__((ext_vector_type(8))) short short8;   // 8 bf16 (4 VGPRs)
typedef __attribute__((ext_vector_type(4))) float f32x4;    // MFMA acc

__device__ __forceinline__ unsigned short f2bf(float f) {
    unsigned int u = __float_as_uint(f);
    return (unsigned short)((u + 0x7FFFu + ((u >> 16) & 1u)) >> 16);
}

// single-wave LDS fence: legal ONLY for 64-thread (one-wave) blocks.
__device__ __forceinline__ void wave_lds_fence() {
    __asm__ __volatile__("s_waitcnt lgkmcnt(0)" ::: "memory");
    __builtin_amdgcn_wave_barrier();
}

// fire-and-forget global->LDS (no dest VGPR; cannot be sunk or pinned wrong)
#define GLD16(gp, lp) __builtin_amdgcn_global_load_lds(                        \
    (const __attribute__((address_space(1))) void*)(gp),                       \
    (__attribute__((address_space(3))) void*)(lp), 16, 0, 0)

// ---------------------------------------------------------------------------
// prep: W fp32 [768 x 50] -> Bt bf16 [64 cols][768 k]; zero out[0] for atomics
// ---------------------------------------------------------------------------
__global__ __launch_bounds__(256) void wprep_kernel(const float* __restrict__ W,
                                                    unsigned short* __restrict__ Bt,
                                                    float* __restrict__ out0) {
    int idx = blockIdx.x * 256 + threadIdx.x;
    if (idx == 0) out0[0] = 0.f;
    if (idx < 64 * DIM) {
        int c = idx / DIM;
        int k = idx - c * DIM;
        float v = (c < NLAB) ? W[k * NLAB + c] : 0.f;
        Bt[idx] = f2bf(v);
    }
}

// ---------------------------------------------------------------------------
// GEMM: 512 thr / 8 waves, tile 128x64, dbuf LDS. Epilogue also writes
// exp(logits) to an ALIGNED, 64-float-stride workspace buffer (eexp).
// ---------------------------------------------------------------------------
#define AST 36
#define BSTC 40

__global__ __launch_bounds__(512)
void gemm_kernel(
    const float* __restrict__ A,
    const unsigned short* __restrict__ Bt,
    const float* __restrict__ bias,
    float* __restrict__ out,
    float* __restrict__ eexp)                 // may be null; stride EEXS
{
    __shared__ float As[2][128 * AST];
    __shared__ short Bs[2][64 * BSTC];

    const int tid = threadIdx.x;
    const int wave = tid >> 6;
    const int lane = tid & 63;
    const int m = lane & 15;
    const int q = lane >> 4;
    const int row0 = blockIdx.x * 128;

    const int r0s = tid >> 2;
    const int c0s = (tid & 3) * 8;
    const int bcol = tid >> 3;
    const int bkk = (tid & 7) * 4;

    f32x4 acc0 = {0.f,0.f,0.f,0.f}, acc1 = {0.f,0.f,0.f,0.f};
    f32x4 acc2 = {0.f,0.f,0.f,0.f}, acc3 = {0.f,0.f,0.f,0.f};

    {
        *(float4*)&As[0][r0s * AST + c0s]     = *(const float4*)(A + (size_t)(row0 + r0s) * DIM + c0s);
        *(float4*)&As[0][r0s * AST + c0s + 4] = *(const float4*)(A + (size_t)(row0 + r0s) * DIM + c0s + 4);
        *(short4*)&Bs[0][bcol * BSTC + bkk]   = *(const short4*)(Bt + (size_t)bcol * DIM + bkk);
    }
    __syncthreads();

    int buf = 0;
    for (int ch = 0; ch < DIM / 32; ++ch) {
        const int k0n = (ch + 1) * 32;
        const bool havenext = (ch < DIM / 32 - 1);
        float4 pa0, pa1;
        short4 pb;
        if (havenext) {
            pa0 = *(const float4*)(A + (size_t)(row0 + r0s) * DIM + k0n + c0s);
            pa1 = *(const float4*)(A + (size_t)(row0 + r0s) * DIM + k0n + c0s + 4);
            pb  = *(const short4*)(Bt + (size_t)bcol * DIM + k0n + bkk);
        }

        const short8 bq0 = *(const short8*)&Bs[buf][( 0 + m) * BSTC + q * 8];
        const short8 bq1 = *(const short8*)&Bs[buf][(16 + m) * BSTC + q * 8];
        const short8 bq2 = *(const short8*)&Bs[buf][(32 + m) * BSTC + q * 8];
        const short8 bq3 = *(const short8*)&Bs[buf][(48 + m) * BSTC + q * 8];

        {
            const int rr = wave * 16 + m;
            const float4 xa = *(const float4*)&As[buf][rr * AST + q * 8];
            const float4 xb = *(const float4*)&As[buf][rr * AST + q * 8 + 4];
            short8 af;
            af[0] = (short)f2bf(xa.x); af[1] = (short)f2bf(xa.y);
            af[2] = (short)f2bf(xa.z); af[3] = (short)f2bf(xa.w);
            af[4] = (short)f2bf(xb.x); af[5] = (short)f2bf(xb.y);
            af[6] = (short)f2bf(xb.z); af[7] = (short)f2bf(xb.w);
            acc0 = __builtin_amdgcn_mfma_f32_16x16x32_bf16(af, bq0, acc0, 0, 0, 0);
            acc1 = __builtin_amdgcn_mfma_f32_16x16x32_bf16(af, bq1, acc1, 0, 0, 0);
            acc2 = __builtin_amdgcn_mfma_f32_16x16x32_bf16(af, bq2, acc2, 0, 0, 0);
            acc3 = __builtin_amdgcn_mfma_f32_16x16x32_bf16(af, bq3, acc3, 0, 0, 0);
        }

        if (havenext) {
            const int nb = buf ^ 1;
            *(float4*)&As[nb][r0s * AST + c0s]     = pa0;
            *(float4*)&As[nb][r0s * AST + c0s + 4] = pa1;
            *(short4*)&Bs[nb][bcol * BSTC + bkk]   = pb;
        }
        __syncthreads();
        buf ^= 1;
    }

    const int rb = row0 + wave * 16 + q * 4;
#pragma unroll
    for (int nt = 0; nt < 4; ++nt) {
        const f32x4 av = (nt == 0) ? acc0 : (nt == 1) ? acc1 : (nt == 2) ? acc2 : acc3;
        const int col = nt * 16 + m;
        if (col < NLAB) {
            const float bv = bias[col];
#pragma unroll
            for (int r = 0; r < 4; ++r) {
                const float v = av[r] + bv;
                out[(size_t)(rb + r) * NLAB + col] = v;
                if (eexp) eexp[(size_t)(rb + r) * EEXS + col] = __expf(v);
            }
        }
    }
}

// ---------------------------------------------------------------------------
// CRF v14: MFMA scan + global_load_lds emission ring (counted vmcnt).
// R7 lesson: "+v" pins force vmcnt(0) at issue (asm consumes the value) ->
// worse. v14 uses fire-and-forget global_load_lds (no dest reg, can't sink):
// 4-slot LDS ring, 4KB/slot (16 batches x EEXS floats); per step issue 4
// gload_lds for row t+5, wait `s_waitcnt vmcnt(12)` before reading row t+1's
// slot (loads stay >=4 steps in flight; m135 semantics). Chunk layout is
// XOR-permuted on the GLOBAL SOURCE side (linear LDS dest, rule #21) so the
// ds_read_b128 readback is <=2-way bank-conflicted. One 16-float register
// stage; no pressure, nothing to sink.
// ---------------------------------------------------------------------------
#define LOG2E 1.44269504088896340736f
#define LN2   0.69314718055994530942f

template<bool EEX>
__global__ __launch_bounds__(64) __attribute__((amdgpu_waves_per_eu(1, 1)))
void crf_kernel(
    const float* __restrict__ logits,
    const float* __restrict__ eex,
    const int* __restrict__ labels,
    const void* __restrict__ maskp,
    const float* __restrict__ startT,
    const float* __restrict__ endT,
    const float* __restrict__ trans,
    float* __restrict__ out0) {
    const int lane = threadIdx.x;
    const int b16 = lane & 15;           // batch within block
    const int g = lane >> 4;             // quad group
    const int b = blockIdx.x * 16 + b16; // global batch

    __shared__ __align__(16) unsigned short X[16 * 64];     // [batch][label] bf16
    __shared__ __align__(16) float RING[4 * 16 * EEXS];     // 4 slots x 4KB
    char* xc = (char*)X;
    char* ringc = (char*)RING;

    // ---- len_b: chunked mask scan (chunk c = g covers 128 t's) ----
    const int probe = ((const int*)maskp)[0];
    int len = 0;
    {
        const int t0 = g * 128;
        if (probe == 1) {
            const int* mk = (const int*)maskp + (size_t)b * TLEN + t0;
#pragma unroll 8
            for (int i = 0; i < 128; ++i) len += (mk[i] != 0);
        } else if (probe == 0x01010101) {
            const unsigned char* mk = (const unsigned char*)maskp + (size_t)b * TLEN + t0;
#pragma unroll 8
            for (int i = 0; i < 128; ++i) len += (mk[i] != 0);
        } else if (probe == 0x3F803F80) {
            const unsigned short* mk = (const unsigned short*)maskp + (size_t)b * TLEN + t0;
#pragma unroll 8
            for (int i = 0; i < 128; ++i) len += (mk[i] != 0);
        } else {
            const float* mk = (const float*)maskp + (size_t)b * TLEN + t0;
#pragma unroll 8
            for (int i = 0; i < 128; ++i) len += (mk[i] != 0.f);
        }
    }
    len += __shfl_xor(len, 16, 64);
    len += __shfl_xor(len, 32, 64);
    int lenmax = len;
    { int o = __shfl_xor(lenmax, 1, 64); lenmax = lenmax > o ? lenmax : o; }
    { int o = __shfl_xor(lenmax, 2, 64); lenmax = lenmax > o ? lenmax : o; }
    { int o = __shfl_xor(lenmax, 4, 64); lenmax = lenmax > o ? lenmax : o; }
    { int o = __shfl_xor(lenmax, 8, 64); lenmax = lenmax > o ? lenmax : o; }
    const int lm1 = lenmax - 1;

    // ---- E^T fragments: A[m][k] = exp(trans[k][m]), hi/lo bf16, zero-pad ----
    short8 ah00, ah01, ah02, ah03, ah10, ah11, ah12, ah13;
    short8 al00, al01, al02, al03, al10, al11, al12, al13;
#define MKFRAG(DH, DL, KT, MT) { short8 h, l;                                   \
    _Pragma("unroll")                                                           \
    for (int j = 0; j < 8; ++j) {                                               \
        const int k = 32 * KT + 8 * g + j; const int m = 16 * MT + b16;         \
        float e = 0.f;                                                          \
        if (k < NLAB && m < NLAB) e = __expf(trans[k * NLAB + m]);              \
        const unsigned short hb = f2bf(e);                                      \
        const float ef = __uint_as_float((unsigned)hb << 16);                   \
        const unsigned short lb = f2bf(e - ef);                                 \
        h[j] = (short)hb; l[j] = (short)lb;                                     \
    } DH = h; DL = l; }
    MKFRAG(ah00, al00, 0, 0) MKFRAG(ah01, al01, 0, 1)
    MKFRAG(ah02, al02, 0, 2) MKFRAG(ah03, al03, 0, 3)
    MKFRAG(ah10, al10, 1, 0) MKFRAG(ah11, al11, 1, 1)
    MKFRAG(ah12, al12, 1, 2) MKFRAG(ah13, al13, 1, 3)

    // ---- addresses / per-lane label maps ----
    const int rowbase = b16 * 128;
    const int swz = (b16 & 7) << 4;
    int wby[4];
    int emo[4][4];
    bool vmask[4][4];
#pragma unroll
    for (int mt = 0; mt < 4; ++mt) {
        wby[mt] = rowbase + ((32 * mt + 8 * g) ^ swz);
#pragma unroll
        for (int r = 0; r < 4; ++r) {
            const int L = 16 * mt + 4 * g + r;
            emo[mt][r] = (L < NLAB) ? L : (NLAB - 1);
            vmask[mt][r] = (L < NLAB);
        }
    }
    const int rby0 = rowbase + ((16 * g)      ^ swz);
    const int rby1 = rowbase + ((64 + 16 * g) ^ swz);

    // ring read offsets: lane (b16,g), mt -> chunk b16*16 + ((4mt+g)^(b16&7))
    int rd0, rd1, rd2, rd3;
    {
        const int xk = b16 & 7;
        rd0 = b16 * 256 + (((0 + g) ^ xk) << 4);
        rd1 = b16 * 256 + (((4 + g) ^ xk) << 4);
        rd2 = b16 * 256 + (((8 + g) ^ xk) << 4);
        rd3 = b16 * 256 + (((12 + g) ^ xk) << 4);
    }
    // gload source pointers: instruction i, lane -> chunk c=i*64+lane,
    // batch bw=c>>4 (within block), f4 = (c&15)^(bw&7)
    const float *gp0, *gp1, *gp2, *gp3;
    if constexpr (EEX) {
        const int c0 = 0 * 64 + lane, c1 = 1 * 64 + lane;
        const int c2 = 2 * 64 + lane, c3 = 3 * 64 + lane;
#define GSRC(c) (eex + (size_t)(blockIdx.x * 16 + ((c) >> 4)) * TLEN * EEXS     \
                     + (size_t)((((c) & 15) ^ (((c) >> 4) & 7)) << 2))
        gp0 = GSRC(c0); gp1 = GSRC(c1); gp2 = GSRC(c2); gp3 = GSRC(c3);
#undef GSRC
    }
#define GLOAD_ROW(row, slot) {                                                  \
        const size_t ro_ = (size_t)(row) * EEXS;                                \
        char* lb_ = ringc + (slot) * 4096;                                      \
        GLD16(gp0 + ro_, lb_);                                                  \
        GLD16(gp1 + ro_, lb_ + 1024);                                           \
        GLD16(gp2 + ro_, lb_ + 2048);                                           \
        GLD16(gp3 + ro_, lb_ + 3072);                                           \
    }

    const float* emb = logits + (size_t)b * TLEN * NLAB;

    // ---- prologue: alpha0 = startT + em[0]; X0 = exp(a0 - a0[label0]) ----
    float a0[4][4];
#pragma unroll
    for (int mt = 0; mt < 4; ++mt)
#pragma unroll
        for (int r = 0; r < 4; ++r)
            a0[mt][r] = startT[emo[mt][r]] + emb[emo[mt][r]];
    const float a00 = __int_as_float(
        __builtin_amdgcn_ds_bpermute(b16 * 4, __float_as_int(a0[0][0])));
    float A = a00;

#pragma unroll
    for (int mt = 0; mt < 4; ++mt) {
        float w0 = vmask[mt][0] ? __expf(a0[mt][0] - a00) : 0.f;
        float w1 = vmask[mt][1] ? __expf(a0[mt][1] - a00) : 0.f;
        float w2 = vmask[mt][2] ? __expf(a0[mt][2] - a00) : 0.f;
        float w3 = vmask[mt][3] ? __expf(a0[mt][3] - a00) : 0.f;
        unsigned int u0, u1;
        asm("v_cvt_pk_bf16_f32 %0, %1, %2" : "=v"(u0) : "v"(w0), "v"(w1));
        asm("v_cvt_pk_bf16_f32 %0, %1, %2" : "=v"(u1) : "v"(w2), "v"(w3));
        uint2 p; p.x = u0; p.y = u1;
        *(uint2*)(xc + wby[mt]) = p;
    }
    wave_lds_fence();
    short8 xb0 = *(const short8*)(xc + rby0);
    short8 xb1 = *(const short8*)(xc + rby1);

    // emission stage s0 = em[1] (registers); ring covers t>=2
    float4 s0a, s0b, s0c, s0d;
    if constexpr (EEX) {
        const float* ep = eex + (size_t)b * TLEN * EEXS + EEXS;  // row 1
        s0a = *(const float4*)(ep + 4 * g);
        s0b = *(const float4*)(ep + 16 + 4 * g);
        s0c = *(const float4*)(ep + 32 + 4 * g);
        s0d = *(const float4*)(ep + 48 + 4 * g);
        // prologue prefetch rows 2..5 -> slots 2,3,0,1
        GLOAD_ROW((2 < lm1 ? 2 : lm1), 2)
        GLOAD_ROW((3 < lm1 ? 3 : lm1), 3)
        GLOAD_ROW((4 < lm1 ? 4 : lm1), 0)
        GLOAD_ROW((5 < lm1 ? 5 : lm1), 1)
    } else {
        const float* ep = emb + NLAB;
        s0a.x = ep[emo[0][0]]; s0a.y = ep[emo[0][1]]; s0a.z = ep[emo[0][2]]; s0a.w = ep[emo[0][3]];
        s0b.x = ep[emo[1][0]]; s0b.y = ep[emo[1][1]]; s0b.z = ep[emo[1][2]]; s0b.w = ep[emo[1][3]];
        s0c.x = ep[emo[2][0]]; s0c.y = ep[emo[2][1]]; s0c.z = ep[emo[2][2]]; s0c.w = ep[emo[2][3]];
        s0d.x = ep[emo[3][0]]; s0d.y = ep[emo[3][1]]; s0d.z = ep[emo[3][2]]; s0d.w = ep[emo[3][3]];
    }

    float vwf = 1.0f;   // raw scale X(t-1)[label0]; exp(a00-a00)=1 at t=1
    const f32x4 z4 = {0.f, 0.f, 0.f, 0.f};

#pragma unroll 2
    for (int t = 1; t < lenmax; ++t) {
        const bool act = (t < len);
        const float lg2v = __log2f(vwf);
        const float rv = __builtin_amdgcn_rcpf(vwf);
        A += act ? lg2v * LN2 : 0.f;

        // pe = exp(em)/v, masked (select kills pad garbage incl. NaN)
        float pe[4][4];
#pragma unroll
        for (int mt = 0; mt < 4; ++mt) {
            const float4 sv = (mt == 0) ? s0a : (mt == 1) ? s0b : (mt == 2) ? s0c : s0d;
#pragma unroll
            for (int r = 0; r < 4; ++r) {
                const float se = (r == 0) ? sv.x : (r == 1) ? sv.y : (r == 2) ? sv.z : sv.w;
                float p;
                if constexpr (EEX) p = se * rv;
                else p = __builtin_amdgcn_exp2f(fmaf(se, LOG2E, -lg2v));
                pe[mt][r] = vmask[mt][r] ? p : 0.f;
            }
        }

        // r = E^T X : hi/lo split accumulators, chains of depth 2
        f32x4 h0 = __builtin_amdgcn_mfma_f32_16x16x32_bf16(ah00, xb0, z4, 0, 0, 0);
        h0 = __builtin_amdgcn_mfma_f32_16x16x32_bf16(ah10, xb1, h0, 0, 0, 0);
        f32x4 l0 = __builtin_amdgcn_mfma_f32_16x16x32_bf16(al00, xb0, z4, 0, 0, 0);
        l0 = __builtin_amdgcn_mfma_f32_16x16x32_bf16(al10, xb1, l0, 0, 0, 0);
        f32x4 h1 = __builtin_amdgcn_mfma_f32_16x16x32_bf16(ah01, xb0, z4, 0, 0, 0);
        h1 = __builtin_amdgcn_mfma_f32_16x16x32_bf16(ah11, xb1, h1, 0, 0, 0);
        f32x4 l1 = __builtin_amdgcn_mfma_f32_16x16x32_bf16(al01, xb0, z4, 0, 0, 0);
        l1 = __builtin_amdgcn_mfma_f32_16x16x32_bf16(al11, xb1, l1, 0, 0, 0);
        f32x4 h2 = __builtin_amdgcn_mfma_f32_16x16x32_bf16(ah02, xb0, z4, 0, 0, 0);
        h2 = __builtin_amdgcn_mfma_f32_16x16x32_bf16(ah12, xb1, h2, 0, 0, 0);
        f32x4 l2 = __builtin_amdgcn_mfma_f32_16x16x32_bf16(al02, xb0, z4, 0, 0, 0);
        l2 = __builtin_amdgcn_mfma_f32_16x16x32_bf16(al12, xb1, l2, 0, 0, 0);
        f32x4 h3 = __builtin_amdgcn_mfma_f32_16x16x32_bf16(ah03, xb0, z4, 0, 0, 0);
        h3 = __builtin_amdgcn_mfma_f32_16x16x32_bf16(ah13, xb1, h3, 0, 0, 0);
        f32x4 l3 = __builtin_amdgcn_mfma_f32_16x16x32_bf16(al03, xb0, z4, 0, 0, 0);
        l3 = __builtin_amdgcn_mfma_f32_16x16x32_bf16(al13, xb1, l3, 0, 0, 0);

        const float w00 = (h0[0] + l0[0]) * pe[0][0];
        const float w01 = (h0[1] + l0[1]) * pe[0][1];
        const float w02 = (h0[2] + l0[2]) * pe[0][2];
        const float w03 = (h0[3] + l0[3]) * pe[0][3];
        const float w10 = (h1[0] + l1[0]) * pe[1][0];
        const float w11 = (h1[1] + l1[1]) * pe[1][1];
        const float w12 = (h1[2] + l1[2]) * pe[1][2];
        const float w13 = (h1[3] + l1[3]) * pe[1][3];
        const float w20 = (h2[0] + l2[0]) * pe[2][0];
        const float w21 = (h2[1] + l2[1]) * pe[2][1];
        const float w22 = (h2[2] + l2[2]) * pe[2][2];
        const float w23 = (h2[3] + l2[3]) * pe[2][3];
        const float w30 = (h3[0] + l3[0]) * pe[3][0];
        const float w31 = (h3[1] + l3[1]) * pe[3][1];
        const float w32 = (h3[2] + l3[2]) * pe[3][2];
        const float w33 = (h3[3] + l3[3]) * pe[3][3];

        // next-step scale: raw fp32 label0 value, broadcast down the column
        const float vwn = __int_as_float(
            __builtin_amdgcn_ds_bpermute(b16 * 4, __float_as_int(w00)));

        uint2 p0, p1, p2, p3;
        asm("v_cvt_pk_bf16_f32 %0, %1, %2" : "=v"(p0.x) : "v"(w00), "v"(w01));
        asm("v_cvt_pk_bf16_f32 %0, %1, %2" : "=v"(p0.y) : "v"(w02), "v"(w03));
        asm("v_cvt_pk_bf16_f32 %0, %1, %2" : "=v"(p1.x) : "v"(w10), "v"(w11));
        asm("v_cvt_pk_bf16_f32 %0, %1, %2" : "=v"(p1.y) : "v"(w12), "v"(w13));
        asm("v_cvt_pk_bf16_f32 %0, %1, %2" : "=v"(p2.x) : "v"(w20), "v"(w21));
        asm("v_cvt_pk_bf16_f32 %0, %1, %2" : "=v"(p2.y) : "v"(w22), "v"(w23));
        asm("v_cvt_pk_bf16_f32 %0, %1, %2" : "=v"(p3.x) : "v"(w30), "v"(w31));
        asm("v_cvt_pk_bf16_f32 %0, %1, %2" : "=v"(p3.y) : "v"(w32), "v"(w33));

        if (act) {   // frozen batches keep their previous X
            *(uint2*)(xc + wby[0]) = p0;
            *(uint2*)(xc + wby[1]) = p1;
            *(uint2*)(xc + wby[2]) = p2;
            *(uint2*)(xc + wby[3]) = p3;
        }

        if constexpr (EEX) {
            // slot for row t+1 was filled 4 steps ago; 12 newer loads in flight
            asm volatile("s_waitcnt vmcnt(12)" ::: "memory");
            const int slot = (t + 1) & 3;
            const char* sb = ringc + slot * 4096;
            const float4 n0 = *(const float4*)(sb + rd0);
            const float4 n1 = *(const float4*)(sb + rd1);
            const float4 n2 = *(const float4*)(sb + rd2);
            const float4 n3 = *(const float4*)(sb + rd3);
            wave_lds_fence();                 // drains X writes + ring reads
            xb0 = *(const short8*)(xc + rby0);
            xb1 = *(const short8*)(xc + rby1);
            int rn = t + 5; rn = (rn < lm1) ? rn : lm1;
            GLOAD_ROW(rn, slot)               // refill slot for row t+5
            s0a = n0; s0b = n1; s0c = n2; s0d = n3;
        } else {
            wave_lds_fence();
            xb0 = *(const short8*)(xc + rby0);
            xb1 = *(const short8*)(xc + rby1);
            int tn = t + 1; tn = (tn < lm1) ? tn : lm1;
            const float* ep = emb + (size_t)(tn < lenmax ? tn : lm1) * NLAB;
            s0a.x = ep[emo[0][0]]; s0a.y = ep[emo[0][1]]; s0a.z = ep[emo[0][2]]; s0a.w = ep[emo[0][3]];
            s0b.x = ep[emo[1][0]]; s0b.y = ep[emo[1][1]]; s0b.z = ep[emo[1][2]]; s0b.w = ep[emo[1][3]];
            s0c.x = ep[emo[2][0]]; s0c.y = ep[emo[2][1]]; s0c.z = ep[emo[2][2]]; s0c.w = ep[emo[2][3]];
            s0d.x = ep[emo[3][0]]; s0d.y = ep[emo[3][1]]; s0d.z = ep[emo[3][2]]; s0d.w = ep[emo[3][3]];
        }
        vwf = vwn;
    }

    // ---- den = A + log( sum_j X[j][b] * exp(endT[j]) ) ----
    float part = 0.f;
#pragma unroll
    for (int j = 0; j < 8; ++j) {
        const int k1 = 32 + 8 * g + j;
        const float x0 = __uint_as_float((unsigned)(unsigned short)xb0[j] << 16);
        const float x1 = __uint_as_float((unsigned)(unsigned short)xb1[j] << 16);
        const float e0 = __expf(endT[8 * g + j]);
        float e1 = 0.f;
        if (k1 < NLAB) e1 = __expf(endT[k1]);
        part = fmaf(x0, e0, part);
        part = fmaf(x1, e1, part);
    }
    part += __shfl_xor(part, 16, 64);
    part += __shfl_xor(part, 32, 64);
    const float den = A + __logf(part);

    // ---- numerator: gold path, chunked over g ----
    const int* tg = labels + (size_t)b * TLEN;
    float num = 0.f;
    {
        const int t0 = g * 128;
#pragma unroll 8
        for (int i = 0; i < 128; ++i) {
            const int t = t0 + i;
            if (t < len) {
                const int tag = tg[t];
                num += emb[(size_t)t * NLAB + tag];
                if (t >= 1) num += trans[tg[t - 1] * NLAB + tag];
            }
        }
    }
    num += __shfl_xor(num, 16, 64);
    num += __shfl_xor(num, 32, 64);
    if (g == 0) {
        num += startT[tg[0]] + endT[tg[len - 1]];
        atomicAdd(out0, (den - num) * (1.0f / BATCH));
    }
}

extern "C" void kernel_launch(void* const* d_in, const int* in_sizes, int n_in,
                              void* d_out, int out_size, void* d_ws, size_t ws_size,
                              hipStream_t stream) {
    (void)in_sizes; (void)n_in; (void)out_size;
    const float* emb    = (const float*)d_in[0];
    const int*   labels = (const int*)d_in[1];
    const void*  mask   = d_in[2];
    const float* W      = (const float*)d_in[3];
    const float* bias   = (const float*)d_in[4];
    const float* startT = (const float*)d_in[5];
    const float* endT   = (const float*)d_in[6];
    const float* trans  = (const float*)d_in[7];

    float* out    = (float*)d_out;
    float* logits = out + 1;
    unsigned short* Bt = (unsigned short*)((char*)d_ws + 512);   // 96 KiB bf16 W^T
    float* eex = (float*)((char*)d_ws + (128 << 10));            // padded exp(logits)

    const size_t need = (size_t)(128 << 10)
                      + sizeof(float) * ((size_t)BATCH * TLEN * EEXS + 256);
    const bool use_eex = (ws_size >= need);

    wprep_kernel<<<(64 * DIM + 255) / 256, 256, 0, stream>>>(W, Bt, out);
    gemm_kernel<<<(BATCH * TLEN) / 128, 512, 0, stream>>>(emb, Bt, bias, logits,
                                                          use_eex ? eex : nullptr);
    if (use_eex)
        crf_kernel<true><<<BATCH / 16, 64, 0, stream>>>(logits, eex, labels, mask,
                                                        startT, endT, trans, out);
    else
        crf_kernel<false><<<BATCH / 16, 64, 0, stream>>>(logits, nullptr, labels, mask,
                                                         startT, endT, trans, out);
}

// Round 9
// 252.660 us; speedup vs baseline: 2.2830x; 1.8462x over previous
//
#include <hip/hip_runtime.h>
#include <hip/hip_bf16.h>
#include <math.h>

#define BATCH 64
#define TLEN 512
#define DIM 768
#define NLAB 50
#define NCH 16     // chunks over time
#define CHL 32     // steps per chunk

typedef __attribute__((ext_vector_type(8))) short short8;   // 8 bf16 (4 VGPRs)
typedef __attribute__((ext_vector_type(4))) float f32x4;    // MFMA acc

__device__ __forceinline__ unsigned short f2bf(float f) {
    unsigned int u = __float_as_uint(f);
    return (unsigned short)((u + 0x7FFFu + ((u >> 16) & 1u)) >> 16);
}

// single-wave LDS fence: legal ONLY for 64-thread (one-wave) blocks.
__device__ __forceinline__ void wave_lds_fence() {
    __asm__ __volatile__("s_waitcnt lgkmcnt(0)" ::: "memory");
    __builtin_amdgcn_wave_barrier();
}

// fire-and-forget global->LDS, 4B/lane
#define GLD4(gp, lp) __builtin_amdgcn_global_load_lds(                         \
    (const __attribute__((address_space(1))) void*)(gp),                       \
    (__attribute__((address_space(3))) void*)(lp), 4, 0, 0)

__device__ __forceinline__ float wave_sum(float v) {
#pragma unroll
    for (int off = 32; off > 0; off >>= 1) v += __shfl_xor(v, off, 64);
    return v;
}
__device__ __forceinline__ float wave_max(float v) {
#pragma unroll
    for (int off = 32; off > 0; off >>= 1) v = fmaxf(v, __shfl_xor(v, off, 64));
    return v;
}

// full-wave contiguous-prefix length of mask row b (dtype-sniffed)
__device__ __forceinline__ int mask_len(const void* maskp, int b, int lane) {
    const int probe = ((const int*)maskp)[0];
    int len = 0;
    if (probe == 1) {
        const int* mk = (const int*)maskp + (size_t)b * TLEN;
#pragma unroll
        for (int it = 0; it < 8; ++it)
            len += (int)__popcll(__ballot(mk[lane + it * 64] != 0));
    } else if (probe == 0x01010101) {
        const unsigned char* mk = (const unsigned char*)maskp + (size_t)b * TLEN;
#pragma unroll
        for (int it = 0; it < 8; ++it)
            len += (int)__popcll(__ballot(mk[lane + it * 64] != 0));
    } else if (probe == 0x3F803F80) {
        const unsigned short* mk = (const unsigned short*)maskp + (size_t)b * TLEN;
#pragma unroll
        for (int it = 0; it < 8; ++it)
            len += (int)__popcll(__ballot(mk[lane + it * 64] != 0));
    } else {
        const float* mk = (const float*)maskp + (size_t)b * TLEN;
#pragma unroll
        for (int it = 0; it < 8; ++it)
            len += (int)__popcll(__ballot(mk[lane + it * 64] != 0.f));
    }
    return len;
}

// ---------------------------------------------------------------------------
// prep: W fp32 [768 x 50] -> Bt bf16 [64 cols][768 k]; zero out[0] for atomics
// ---------------------------------------------------------------------------
__global__ __launch_bounds__(256) void wprep_kernel(const float* __restrict__ W,
                                                    unsigned short* __restrict__ Bt,
                                                    float* __restrict__ out0) {
    int idx = blockIdx.x * 256 + threadIdx.x;
    if (idx == 0) out0[0] = 0.f;
    if (idx < 64 * DIM) {
        int c = idx / DIM;
        int k = idx - c * DIM;
        float v = (c < NLAB) ? W[k * NLAB + c] : 0.f;
        Bt[idx] = f2bf(v);
    }
}

// ---------------------------------------------------------------------------
// GEMM (R2 version, eex removed): 512 thr / 8 waves, tile 128x64, dbuf LDS.
// ---------------------------------------------------------------------------
#define AST 36
#define BSTC 40

__global__ __launch_bounds__(512)
void gemm_kernel(
    const float* __restrict__ A,
    const unsigned short* __restrict__ Bt,
    const float* __restrict__ bias,
    float* __restrict__ out)
{
    __shared__ float As[2][128 * AST];
    __shared__ short Bs[2][64 * BSTC];

    const int tid = threadIdx.x;
    const int wave = tid >> 6;
    const int lane = tid & 63;
    const int m = lane & 15;
    const int q = lane >> 4;
    const int row0 = blockIdx.x * 128;

    const int r0s = tid >> 2;
    const int c0s = (tid & 3) * 8;
    const int bcol = tid >> 3;
    const int bkk = (tid & 7) * 4;

    f32x4 acc0 = {0.f,0.f,0.f,0.f}, acc1 = {0.f,0.f,0.f,0.f};
    f32x4 acc2 = {0.f,0.f,0.f,0.f}, acc3 = {0.f,0.f,0.f,0.f};

    {
        *(float4*)&As[0][r0s * AST + c0s]     = *(const float4*)(A + (size_t)(row0 + r0s) * DIM + c0s);
        *(float4*)&As[0][r0s * AST + c0s + 4] = *(const float4*)(A + (size_t)(row0 + r0s) * DIM + c0s + 4);
        *(short4*)&Bs[0][bcol * BSTC + bkk]   = *(const short4*)(Bt + (size_t)bcol * DIM + bkk);
    }
    __syncthreads();

    int buf = 0;
    for (int ch = 0; ch < DIM / 32; ++ch) {
        const int k0n = (ch + 1) * 32;
        const bool havenext = (ch < DIM / 32 - 1);
        float4 pa0, pa1;
        short4 pb;
        if (havenext) {
            pa0 = *(const float4*)(A + (size_t)(row0 + r0s) * DIM + k0n + c0s);
            pa1 = *(const float4*)(A + (size_t)(row0 + r0s) * DIM + k0n + c0s + 4);
            pb  = *(const short4*)(Bt + (size_t)bcol * DIM + k0n + bkk);
        }

        const short8 bq0 = *(const short8*)&Bs[buf][( 0 + m) * BSTC + q * 8];
        const short8 bq1 = *(const short8*)&Bs[buf][(16 + m) * BSTC + q * 8];
        const short8 bq2 = *(const short8*)&Bs[buf][(32 + m) * BSTC + q * 8];
        const short8 bq3 = *(const short8*)&Bs[buf][(48 + m) * BSTC + q * 8];

        {
            const int rr = wave * 16 + m;
            const float4 xa = *(const float4*)&As[buf][rr * AST + q * 8];
            const float4 xb = *(const float4*)&As[buf][rr * AST + q * 8 + 4];
            short8 af;
            af[0] = (short)f2bf(xa.x); af[1] = (short)f2bf(xa.y);
            af[2] = (short)f2bf(xa.z); af[3] = (short)f2bf(xa.w);
            af[4] = (short)f2bf(xb.x); af[5] = (short)f2bf(xb.y);
            af[6] = (short)f2bf(xb.z); af[7] = (short)f2bf(xb.w);
            acc0 = __builtin_amdgcn_mfma_f32_16x16x32_bf16(af, bq0, acc0, 0, 0, 0);
            acc1 = __builtin_amdgcn_mfma_f32_16x16x32_bf16(af, bq1, acc1, 0, 0, 0);
            acc2 = __builtin_amdgcn_mfma_f32_16x16x32_bf16(af, bq2, acc2, 0, 0, 0);
            acc3 = __builtin_amdgcn_mfma_f32_16x16x32_bf16(af, bq3, acc3, 0, 0, 0);
        }

        if (havenext) {
            const int nb = buf ^ 1;
            *(float4*)&As[nb][r0s * AST + c0s]     = pa0;
            *(float4*)&As[nb][r0s * AST + c0s + 4] = pa1;
            *(short4*)&Bs[nb][bcol * BSTC + bkk]   = pb;
        }
        __syncthreads();
        buf ^= 1;
    }

    const int rb = row0 + wave * 16 + q * 4;
#pragma unroll
    for (int nt = 0; nt < 4; ++nt) {
        const f32x4 av = (nt == 0) ? acc0 : (nt == 1) ? acc1 : (nt == 2) ? acc2 : acc3;
        const int col = nt * 16 + m;
        if (col < NLAB) {
            const float bv = bias[col];
#pragma unroll
            for (int r = 0; r < 4; ++r)
                out[(size_t)(rb + r) * NLAB + col] = av[r] + bv;
        }
    }
}

// ---------------------------------------------------------------------------
// CRF v15a (chunk): parallel scan over T. Block (b, c) computes
// Q_c = Pi_{t in chunk, t<len_b} diag(p_t) E^T   (64x64, identity-padded),
// max-normalized per step with logS accumulation. 1024 blocks x 1 wave.
// Layouts are v11-verified patterns: E^T hi/lo A-frags (MKFRAG), C-layout
// -> swizzled LDS write (wby), LDS -> B-frag read (rby); the old batch dim
// (16) is now the start-label dim (64 -> 4 n-tiles). Emissions for the
// whole chunk staged upfront via 32x global_load_lds + one vmcnt(0).
// Output Q_c stored [m][c] bf16 row-major (A-frag-ready for nothing --
// combine is VALU), plus logS[b][c].
// ---------------------------------------------------------------------------
__global__ __launch_bounds__(64) __attribute__((amdgpu_waves_per_eu(1, 1)))
void crf_chunk(const float* __restrict__ logits,
               const void* __restrict__ maskp,
               const float* __restrict__ trans,
               unsigned short* __restrict__ Qws,
               float* __restrict__ logSws) {
    const int bx = blockIdx.x;
    const int b = bx >> 4;          // batch
    const int c = bx & 15;          // chunk
    const int lane = threadIdx.x;
    const int b16 = lane & 15;
    const int g = lane >> 4;

    __shared__ __align__(16) unsigned short Q[64 * 64];   // [start c][label m] swizzled
    __shared__ __align__(16) float EM[CHL * 64];          // staged emission rows
    char* qc = (char*)Q;

    const int len = mask_len(maskp, b, lane);
    const int t0 = 1 + c * CHL;
    int te = t0 + CHL; if (te > len) te = len;

    unsigned short* qg = Qws + (size_t)bx * 4096;         // [m][c] ushorts

    // per-lane label maps (v11)
    int emo[4][4]; bool vmask[4][4];
#pragma unroll
    for (int mt = 0; mt < 4; ++mt)
#pragma unroll
        for (int r = 0; r < 4; ++r) {
            const int L = 16 * mt + 4 * g + r;
            emo[mt][r] = (L < NLAB) ? L : (NLAB - 1);
            vmask[mt][r] = (L < NLAB);
        }

    if (te <= t0) {   // whole chunk masked out -> identity
#pragma unroll
        for (int mt = 0; mt < 4; ++mt)
#pragma unroll
            for (int r = 0; r < 4; ++r) {
                const int m = 16 * mt + 4 * g + r;
#pragma unroll
                for (int nt = 0; nt < 4; ++nt) {
                    const int col = 16 * nt + b16;
                    qg[m * 64 + col] = (m == col) ? (unsigned short)0x3F80 : (unsigned short)0;
                }
            }
        if (lane == 0) logSws[bx] = 0.f;
        return;
    }

    // E^T hi/lo fragments (v11 MKFRAG, array form, fully unrolled)
    short8 ah[4][2], al[4][2];
#pragma unroll
    for (int mt = 0; mt < 4; ++mt)
#pragma unroll
        for (int kt = 0; kt < 2; ++kt) {
            short8 h, l;
#pragma unroll
            for (int j = 0; j < 8; ++j) {
                const int k = 32 * kt + 8 * g + j;
                const int m = 16 * mt + b16;
                float e = 0.f;
                if (k < NLAB && m < NLAB) e = __expf(trans[k * NLAB + m]);
                const unsigned short hb = f2bf(e);
                const float ef = __uint_as_float((unsigned)hb << 16);
                h[j] = (short)hb;
                l[j] = (short)f2bf(e - ef);
            }
            ah[mt][kt] = h; al[mt][kt] = l;
        }

    // swizzled LDS addresses (v11 wby/rby, generalized to 64 rows)
    const int swz = (b16 & 7) << 4;
    int wby[4][4], rby[4][2];
#pragma unroll
    for (int nt = 0; nt < 4; ++nt) {
        const int rowb = (16 * nt + b16) * 128;
#pragma unroll
        for (int mt = 0; mt < 4; ++mt)
            wby[nt][mt] = rowb + ((32 * mt + 8 * g) ^ swz);
#pragma unroll
        for (int kt = 0; kt < 2; ++kt)
            rby[nt][kt] = rowb + ((64 * kt + 16 * g) ^ swz);
    }

    // init Q = I (lane zeroes its own row, then writes its diagonal bf16 1.0)
    {
        uint4 z = {0u, 0u, 0u, 0u};
#pragma unroll
        for (int i = 0; i < 8; ++i)
            *(uint4*)(qc + lane * 128 + i * 16) = z;
        const int boff = 2 * lane;
        const int grp = boff & ~7, wi = boff & 7;
        *(unsigned short*)(qc + lane * 128 + ((grp ^ ((lane & 7) << 4))) + wi) = 0x3F80;
    }

    // stage all chunk emission rows: row i <- logits[b][t0+i][lane] (lane<50)
    const float* embb = logits + (size_t)b * TLEN * NLAB;
    const int nrows = te - t0;
    for (int i = 0; i < nrows; ++i) {
        if (lane < NLAB)
            GLD4(embb + (size_t)(t0 + i) * NLAB + lane, (char*)EM + i * 256);
    }
    asm volatile("s_waitcnt vmcnt(0)" ::: "memory");
    wave_lds_fence();   // Q-init ds_writes + EM visible

    float logS = 0.f;
    const f32x4 z4 = {0.f, 0.f, 0.f, 0.f};

    for (int t = t0; t < te; ++t) {
        // B-frags of current Q
        short8 xbq[4][2];
#pragma unroll
        for (int nt = 0; nt < 4; ++nt)
#pragma unroll
            for (int kt = 0; kt < 2; ++kt)
                xbq[nt][kt] = *(const short8*)(qc + rby[nt][kt]);

        // pe = exp(em[t][m-row]), masked
        const char* emr = (const char*)EM + (t - t0) * 256;
        float pe[4][4];
#pragma unroll
        for (int mt = 0; mt < 4; ++mt) {
            const float4 ev = *(const float4*)(emr + (16 * mt + 4 * g) * 4);
#pragma unroll
            for (int r = 0; r < 4; ++r) {
                const float e = (r == 0) ? ev.x : (r == 1) ? ev.y : (r == 2) ? ev.z : ev.w;
                pe[mt][r] = vmask[mt][r] ? __expf(e) : 0.f;
            }
        }

        // acc[nt][mt] = E^T(hi+lo) x Q
        f32x4 acc[4][4];
#pragma unroll
        for (int nt = 0; nt < 4; ++nt)
#pragma unroll
            for (int mt = 0; mt < 4; ++mt) {
                f32x4 a = __builtin_amdgcn_mfma_f32_16x16x32_bf16(ah[mt][0], xbq[nt][0], z4, 0, 0, 0);
                a = __builtin_amdgcn_mfma_f32_16x16x32_bf16(al[mt][0], xbq[nt][0], a, 0, 0, 0);
                a = __builtin_amdgcn_mfma_f32_16x16x32_bf16(ah[mt][1], xbq[nt][1], a, 0, 0, 0);
                a = __builtin_amdgcn_mfma_f32_16x16x32_bf16(al[mt][1], xbq[nt][1], a, 0, 0, 0);
                acc[nt][mt] = a;
            }

        // pass 1: global max of w = acc*pe
        float mx = 0.f;
#pragma unroll
        for (int nt = 0; nt < 4; ++nt)
#pragma unroll
            for (int mt = 0; mt < 4; ++mt)
#pragma unroll
                for (int r = 0; r < 4; ++r)
                    mx = fmaxf(mx, acc[nt][mt][r] * pe[mt][r]);
        mx = wave_max(mx);
        const float rv = __builtin_amdgcn_rcpf(mx);
        logS += __logf(mx);

        if (t < te - 1) {
            // pass 2: scaled bf16 back into LDS (next step's B operand)
#pragma unroll
            for (int nt = 0; nt < 4; ++nt)
#pragma unroll
                for (int mt = 0; mt < 4; ++mt) {
                    const float w0 = acc[nt][mt][0] * pe[mt][0] * rv;
                    const float w1 = acc[nt][mt][1] * pe[mt][1] * rv;
                    const float w2 = acc[nt][mt][2] * pe[mt][2] * rv;
                    const float w3 = acc[nt][mt][3] * pe[mt][3] * rv;
                    uint2 p;
                    asm("v_cvt_pk_bf16_f32 %0, %1, %2" : "=v"(p.x) : "v"(w0), "v"(w1));
                    asm("v_cvt_pk_bf16_f32 %0, %1, %2" : "=v"(p.y) : "v"(w2), "v"(w3));
                    *(uint2*)(qc + wby[nt][mt]) = p;
                }
            wave_lds_fence();
        } else {
            // final step: store Q_c to workspace, layout [m][c] bf16
#pragma unroll
            for (int mt = 0; mt < 4; ++mt)
#pragma unroll
                for (int r = 0; r < 4; ++r) {
                    const int m = 16 * mt + 4 * g + r;
#pragma unroll
                    for (int nt = 0; nt < 4; ++nt)
                        qg[m * 64 + 16 * nt + b16] =
                            f2bf(acc[nt][mt][r] * pe[mt][r] * rv);
                }
        }
    }
    if (lane == 0) logSws[bx] = logS;
}

// ---------------------------------------------------------------------------
// CRF v15b (combine): per batch (64 blocks x 1 wave), alpha (fp32, LDS,
// lane = label) through the 16 chunk matrices: alpha' = Q_c * alpha with
// max-rescale; A tracks a00-style log. Then den/num/loss (v8 numerator).
// ---------------------------------------------------------------------------
__global__ __launch_bounds__(64) __attribute__((amdgpu_waves_per_eu(1, 1)))
void crf_combine(const float* __restrict__ logits,
                 const int* __restrict__ labels,
                 const void* __restrict__ maskp,
                 const float* __restrict__ startT,
                 const float* __restrict__ endT,
                 const float* __restrict__ trans,
                 const unsigned short* __restrict__ Qws,
                 const float* __restrict__ logSws,
                 float* __restrict__ out0) {
    const int b = blockIdx.x;
    const int lane = threadIdx.x;
    __shared__ __align__(16) float AL[64];

    const int len = mask_len(maskp, b, lane);
    const float* em = logits + (size_t)b * TLEN * NLAB;

    // alpha0 = exp(startT + em[0] - max)
    float a0 = (lane < NLAB) ? (startT[lane] + em[lane]) : -1e30f;
    const float mx0 = wave_max(a0);
    float alpha = (lane < NLAB) ? __expf(a0 - mx0) : 0.f;
    float A = mx0;
    AL[lane] = alpha;
    wave_lds_fence();

    const unsigned short* qb = Qws + (size_t)b * NCH * 4096;
    for (int cc = 0; cc < NCH; ++cc) {
        // this lane's Q row (label m = lane): 64 bf16 = 8x dwordx4
        const unsigned short* qr = qb + cc * 4096 + lane * 64;
        uint4 qv[8];
#pragma unroll
        for (int i = 0; i < 8; ++i)
            qv[i] = *(const uint4*)(qr + i * 8);

        float s = 0.f;
#pragma unroll
        for (int i = 0; i < 8; ++i) {
            const float4 alo = *(const float4*)(AL + 8 * i);       // broadcast
            const float4 ahi = *(const float4*)(AL + 8 * i + 4);
            const uint4 q = qv[i];
            s = fmaf(__uint_as_float(q.x << 16), alo.x, s);
            s = fmaf(__uint_as_float(q.x & 0xFFFF0000u), alo.y, s);
            s = fmaf(__uint_as_float(q.y << 16), alo.z, s);
            s = fmaf(__uint_as_float(q.y & 0xFFFF0000u), alo.w, s);
            s = fmaf(__uint_as_float(q.z << 16), ahi.x, s);
            s = fmaf(__uint_as_float(q.z & 0xFFFF0000u), ahi.y, s);
            s = fmaf(__uint_as_float(q.w << 16), ahi.z, s);
            s = fmaf(__uint_as_float(q.w & 0xFFFF0000u), ahi.w, s);
        }
        const float mxs = wave_max(s);
        A += __logf(mxs) + logSws[b * NCH + cc];
        alpha = s * __builtin_amdgcn_rcpf(mxs);
        wave_lds_fence();            // all lanes done reading AL
        AL[lane] = alpha;
        wave_lds_fence();
    }

    // den = A + log( sum_m alpha_m * exp(endT[m]) )
    const float term = (lane < NLAB) ? alpha * __expf(endT[lane]) : 0.f;
    const float den = A + __logf(wave_sum(term));

    // numerator: gold path (v8 full-wave code)
    const int* tg = labels + (size_t)b * TLEN;
    float num = 0.f;
#pragma unroll
    for (int it = 0; it < 8; ++it) {
        const int t = lane + it * 64;
        if (t < len) {
            const int tag = tg[t];
            num += em[(size_t)t * NLAB + tag];
            if (t >= 1) num += trans[tg[t - 1] * NLAB + tag];
        }
    }
    num = wave_sum(num);
    if (lane == 0) {
        num += startT[tg[0]] + endT[tg[len - 1]];
        atomicAdd(out0, (den - num) * (1.0f / BATCH));
    }
}

extern "C" void kernel_launch(void* const* d_in, const int* in_sizes, int n_in,
                              void* d_out, int out_size, void* d_ws, size_t ws_size,
                              hipStream_t stream) {
    (void)in_sizes; (void)n_in; (void)out_size; (void)ws_size;
    const float* emb    = (const float*)d_in[0];
    const int*   labels = (const int*)d_in[1];
    const void*  mask   = d_in[2];
    const float* W      = (const float*)d_in[3];
    const float* bias   = (const float*)d_in[4];
    const float* startT = (const float*)d_in[5];
    const float* endT   = (const float*)d_in[6];
    const float* trans  = (const float*)d_in[7];

    float* out    = (float*)d_out;
    float* logits = out + 1;
    // ws layout (max end 8,519,680 B <= proven ws_size >= 8,520,704 from R6/R8 EEX runs):
    unsigned short* Bt   = (unsigned short*)((char*)d_ws + 512);      // 96 KiB
    float*          logS = (float*)((char*)d_ws + 99328);             // 4 KiB (64x16)
    unsigned short* Qws  = (unsigned short*)((char*)d_ws + 131072);   // 8 MiB bf16

    wprep_kernel<<<(64 * DIM + 255) / 256, 256, 0, stream>>>(W, Bt, out);
    gemm_kernel<<<(BATCH * TLEN) / 128, 512, 0, stream>>>(emb, Bt, bias, logits);
    crf_chunk<<<BATCH * NCH, 64, 0, stream>>>(logits, mask, trans, Qws, logS);
    crf_combine<<<BATCH, 64, 0, stream>>>(logits, labels, mask, startT, endT, trans,
                                          Qws, logS, out);
}